// Round 1
// baseline (115.216 us; speedup 1.0000x reference)
//
#include <hip/hip_runtime.h>

// SegmentedMean: features [N=2e6, 64] f32, segments [N] int (sorted), out [S=1e5, 64] f32
// out[s] = mean of rows whose segment == s; empty segments -> 0.
//
// One wave (64 lanes) per output segment; lane j owns column j.
// Segment row-ranges precomputed into d_ws as starts[S+1].

__device__ __forceinline__ int lower_bound_dev(const int* __restrict__ a, int n, int v) {
    int lo = 0, hi = n;
    while (lo < hi) {
        int mid = (lo + hi) >> 1;
        if (a[mid] < v) lo = mid + 1; else hi = mid;
    }
    return lo;
}

__global__ void init_starts_kernel(int* __restrict__ starts, int S, int N) {
    int i = blockIdx.x * blockDim.x + threadIdx.x;
    if (i <= S) starts[i] = N;
}

__global__ void fill_starts_kernel(const int* __restrict__ seg, int N,
                                   int* __restrict__ starts) {
    int i = blockIdx.x * blockDim.x + threadIdx.x;
    if (i >= N) return;
    int s = seg[i];
    int sprev = (i == 0) ? -1 : seg[i - 1];
    // this row opens segments (sprev, s]; empty segments in the gap also point here
    for (int t = sprev + 1; t <= s; ++t) starts[t] = i;
}

__global__ __launch_bounds__(256) void seg_mean_kernel(const float* __restrict__ feat,
                                                       const int* __restrict__ starts,
                                                       float* __restrict__ out, int S) {
    int wave = (int)((blockIdx.x * blockDim.x + threadIdx.x) >> 6);
    int lane = threadIdx.x & 63;
    if (wave >= S) return;

    int lo = starts[wave];
    int hi = starts[wave + 1];
    int cnt = hi - lo;

    const float* p = feat + (size_t)lo * 64 + lane;
    float a0 = 0.f, a1 = 0.f, a2 = 0.f, a3 = 0.f;
    int r = lo;
    for (; r + 4 <= hi; r += 4) {
        a0 += p[0];
        a1 += p[64];
        a2 += p[128];
        a3 += p[192];
        p += 256;
    }
    for (; r < hi; ++r) { a0 += *p; p += 64; }
    float acc = (a0 + a1) + (a2 + a3);

    out[(size_t)wave * 64 + lane] = (cnt > 0) ? (acc / (float)cnt) : 0.f;
}

// Fallback if workspace is too small: per-wave binary search for boundaries.
__global__ __launch_bounds__(256) void seg_mean_bs_kernel(const float* __restrict__ feat,
                                                          const int* __restrict__ seg, int N,
                                                          float* __restrict__ out, int S) {
    int wave = (int)((blockIdx.x * blockDim.x + threadIdx.x) >> 6);
    int lane = threadIdx.x & 63;
    if (wave >= S) return;

    int lo = lower_bound_dev(seg, N, wave);
    int hi = lower_bound_dev(seg, N, wave + 1);
    int cnt = hi - lo;

    const float* p = feat + (size_t)lo * 64 + lane;
    float a0 = 0.f, a1 = 0.f, a2 = 0.f, a3 = 0.f;
    int r = lo;
    for (; r + 4 <= hi; r += 4) {
        a0 += p[0];
        a1 += p[64];
        a2 += p[128];
        a3 += p[192];
        p += 256;
    }
    for (; r < hi; ++r) { a0 += *p; p += 64; }
    float acc = (a0 + a1) + (a2 + a3);

    out[(size_t)wave * 64 + lane] = (cnt > 0) ? (acc / (float)cnt) : 0.f;
}

extern "C" void kernel_launch(void* const* d_in, const int* in_sizes, int n_in,
                              void* d_out, int out_size, void* d_ws, size_t ws_size,
                              hipStream_t stream) {
    const float* feat = (const float*)d_in[0];
    const int* seg = (const int*)d_in[1];
    const int N = in_sizes[1];
    const int S = out_size / 64;
    float* out = (float*)d_out;

    const size_t need = (size_t)(S + 1) * sizeof(int);
    const int waves_total = S;
    const int main_blocks = (waves_total * 64 + 255) / 256;

    if (ws_size >= need) {
        int* starts = (int*)d_ws;
        init_starts_kernel<<<(S + 256) / 256, 256, 0, stream>>>(starts, S, N);
        fill_starts_kernel<<<(N + 255) / 256, 256, 0, stream>>>(seg, N, starts);
        seg_mean_kernel<<<main_blocks, 256, 0, stream>>>(feat, starts, out, S);
    } else {
        seg_mean_bs_kernel<<<main_blocks, 256, 0, stream>>>(feat, seg, N, out, S);
    }
}

// Round 2
// 104.458 us; speedup vs baseline: 1.1030x; 1.1030x over previous
//
#include <hip/hip_runtime.h>

// SegmentedMean: features [N=2e6, 64] f32, segments [N] int (sorted), out [S=1e5, 64] f32
// out[s] = mean of rows with segment == s; empty segments -> 0.
//
// Plan: starts[S+1] built in d_ws (one fused kernel), then one wave per
// segment, 4 rows per float4 wave-load (1024 B / instruction), shfl combine.

__device__ __forceinline__ int lower_bound_dev(const int* __restrict__ a, int n, int v) {
    int lo = 0, hi = n;
    while (lo < hi) {
        int mid = (lo + hi) >> 1;
        if (a[mid] < v) lo = mid + 1; else hi = mid;
    }
    return lo;
}

// Fused boundary builder: threads [0,N) write starts[t]=i for t in (seg[i-1], seg[i]];
// threads [N, N+S+1) write starts[t]=N only for t > seg[N-1] (disjoint -> no race).
__global__ void build_starts_kernel(const int* __restrict__ seg, int N, int S,
                                    int* __restrict__ starts) {
    int i = blockIdx.x * blockDim.x + threadIdx.x;
    if (i < N) {
        int s = seg[i];
        int sprev = (i == 0) ? -1 : seg[i - 1];
        for (int t = sprev + 1; t <= s; ++t) starts[t] = i;
    } else {
        int t = i - N;            // 0..S
        if (t <= S) {
            int last = seg[N - 1];
            if (t > last) starts[t] = N;
        }
    }
}

// One wave per segment. Lane i handles row-in-group (i>>4), cols (i&15)*4..+3.
__global__ __launch_bounds__(256) void seg_mean_f4_kernel(const float4* __restrict__ feat4,
                                                          const int* __restrict__ starts,
                                                          float4* __restrict__ out4, int S) {
    int gid = blockIdx.x * blockDim.x + threadIdx.x;
    int wave = gid >> 6;
    int lane = threadIdx.x & 63;
    if (wave >= S) return;

    int lo = starts[wave];
    int hi = starts[wave + 1];
    int cnt = hi - lo;

    // float4 view: row r starts at float4 index r*16. 4 rows = 64 float4.
    const float4* q = feat4 + (size_t)lo * 16 + lane;

    float x0 = 0.f, y0 = 0.f, z0 = 0.f, w0 = 0.f;
    float x1 = 0.f, y1 = 0.f, z1 = 0.f, w1 = 0.f;

    int nfull = cnt >> 2;   // groups of 4 rows
    int k = 0;
    for (; k + 2 <= nfull; k += 2) {
        float4 v0 = q[0];
        float4 v1 = q[64];
        x0 += v0.x; y0 += v0.y; z0 += v0.z; w0 += v0.w;
        x1 += v1.x; y1 += v1.y; z1 += v1.z; w1 += v1.w;
        q += 128;
    }
    if (k < nfull) {
        float4 v0 = q[0];
        x0 += v0.x; y0 += v0.y; z0 += v0.z; w0 += v0.w;
        q += 64;
    }
    int rem = cnt & 3;      // leftover rows: lanes whose row-in-group < rem
    if ((lane >> 4) < rem) {
        float4 v = q[0];
        x1 += v.x; y1 += v.y; z1 += v.z; w1 += v.w;
    }

    float sx = x0 + x1, sy = y0 + y1, sz = z0 + z1, sw = w0 + w1;
    // combine the 4 row-groups (lanes i, i^16, i^32, i^48)
    sx += __shfl_xor(sx, 16); sy += __shfl_xor(sy, 16);
    sz += __shfl_xor(sz, 16); sw += __shfl_xor(sw, 16);
    sx += __shfl_xor(sx, 32); sy += __shfl_xor(sy, 32);
    sz += __shfl_xor(sz, 32); sw += __shfl_xor(sw, 32);

    if ((lane >> 4) == 0) {
        float inv = (cnt > 0) ? 1.f / (float)cnt : 0.f;
        float4 r;
        r.x = sx * inv; r.y = sy * inv; r.z = sz * inv; r.w = sw * inv;
        out4[(size_t)wave * 16 + lane] = r;
    }
}

// Fallback if workspace is too small: per-wave binary search (dword path).
__global__ __launch_bounds__(256) void seg_mean_bs_kernel(const float* __restrict__ feat,
                                                          const int* __restrict__ seg, int N,
                                                          float* __restrict__ out, int S) {
    int wave = (int)((blockIdx.x * blockDim.x + threadIdx.x) >> 6);
    int lane = threadIdx.x & 63;
    if (wave >= S) return;

    int lo = lower_bound_dev(seg, N, wave);
    int hi = lower_bound_dev(seg, N, wave + 1);
    int cnt = hi - lo;

    const float* p = feat + (size_t)lo * 64 + lane;
    float a0 = 0.f, a1 = 0.f, a2 = 0.f, a3 = 0.f;
    int r = lo;
    for (; r + 4 <= hi; r += 4) {
        a0 += p[0];
        a1 += p[64];
        a2 += p[128];
        a3 += p[192];
        p += 256;
    }
    for (; r < hi; ++r) { a0 += *p; p += 64; }
    float acc = (a0 + a1) + (a2 + a3);

    out[(size_t)wave * 64 + lane] = (cnt > 0) ? (acc / (float)cnt) : 0.f;
}

extern "C" void kernel_launch(void* const* d_in, const int* in_sizes, int n_in,
                              void* d_out, int out_size, void* d_ws, size_t ws_size,
                              hipStream_t stream) {
    const float* feat = (const float*)d_in[0];
    const int* seg = (const int*)d_in[1];
    const int N = in_sizes[1];
    const int S = out_size / 64;
    float* out = (float*)d_out;

    const size_t need = (size_t)(S + 1) * sizeof(int);

    if (ws_size >= need) {
        int* starts = (int*)d_ws;
        int total = N + S + 1;
        build_starts_kernel<<<(total + 255) / 256, 256, 0, stream>>>(seg, N, S, starts);
        int main_blocks = (S * 64 + 255) / 256;
        seg_mean_f4_kernel<<<main_blocks, 256, 0, stream>>>(
            (const float4*)feat, starts, (float4*)out, S);
    } else {
        int main_blocks = (S * 64 + 255) / 256;
        seg_mean_bs_kernel<<<main_blocks, 256, 0, stream>>>(feat, seg, N, out, S);
    }
}

// Round 3
// 90.943 us; speedup vs baseline: 1.2669x; 1.1486x over previous
//
#include <hip/hip_runtime.h>

// SegmentedMean: features [N=2e6, 64] f32, segments [N] int32 (sorted), out [S=1e5, 64] f32
// out[s] = mean of rows with segment == s; empty segments -> 0.
//
// starts[S+1] built in d_ws (one fused kernel), then one wave per segment,
// 4 rows per float4 wave-load (1024 B / instruction), unroll x4 for MLP,
// non-temporal feature loads (read-once; don't thrash L2/L3), shfl combine.

typedef float f4 __attribute__((ext_vector_type(4)));

__device__ __forceinline__ int lower_bound_dev(const int* __restrict__ a, int n, int v) {
    int lo = 0, hi = n;
    while (lo < hi) {
        int mid = (lo + hi) >> 1;
        if (a[mid] < v) lo = mid + 1; else hi = mid;
    }
    return lo;
}

// Fused boundary builder: threads [0,N) write starts[t]=i for t in (seg[i-1], seg[i]];
// threads [N, N+S+1) write starts[t]=N only for t > seg[N-1] (disjoint -> no race).
__global__ void build_starts_kernel(const int* __restrict__ seg, int N, int S,
                                    int* __restrict__ starts) {
    int i = blockIdx.x * blockDim.x + threadIdx.x;
    if (i < N) {
        int s = seg[i];
        int sprev = (i == 0) ? -1 : seg[i - 1];
        for (int t = sprev + 1; t <= s; ++t) starts[t] = i;
    } else {
        int t = i - N;            // 0..S
        if (t <= S) {
            int last = seg[N - 1];
            if (t > last) starts[t] = N;
        }
    }
}

// One wave per segment. Lane i handles row-in-group (i>>4), cols (i&15)*4..+3.
__global__ __launch_bounds__(256) void seg_mean_f4_kernel(const f4* __restrict__ feat4,
                                                          const int* __restrict__ starts,
                                                          f4* __restrict__ out4, int S) {
    int gid = blockIdx.x * blockDim.x + threadIdx.x;
    int wave = gid >> 6;
    int lane = threadIdx.x & 63;
    if (wave >= S) return;

    int lo = starts[wave];
    int hi = starts[wave + 1];
    int cnt = hi - lo;

    // f4 view: row r starts at f4 index r*16. 4 rows = 64 f4 (one per lane).
    const f4* q = feat4 + (size_t)lo * 16 + lane;

    f4 a0 = {0.f, 0.f, 0.f, 0.f};
    f4 a1 = {0.f, 0.f, 0.f, 0.f};
    f4 a2 = {0.f, 0.f, 0.f, 0.f};
    f4 a3 = {0.f, 0.f, 0.f, 0.f};

    int nfull = cnt >> 2;   // groups of 4 rows
    int k = 0;
    for (; k + 4 <= nfull; k += 4) {
        f4 v0 = __builtin_nontemporal_load(q);
        f4 v1 = __builtin_nontemporal_load(q + 64);
        f4 v2 = __builtin_nontemporal_load(q + 128);
        f4 v3 = __builtin_nontemporal_load(q + 192);
        a0 += v0; a1 += v1; a2 += v2; a3 += v3;
        q += 256;
    }
    if (k + 2 <= nfull) {
        f4 v0 = __builtin_nontemporal_load(q);
        f4 v1 = __builtin_nontemporal_load(q + 64);
        a0 += v0; a1 += v1;
        q += 128;
        k += 2;
    }
    if (k < nfull) {
        f4 v0 = __builtin_nontemporal_load(q);
        a0 += v0;
        q += 64;
    }
    int rem = cnt & 3;      // leftover rows: lanes whose row-in-group < rem
    if ((lane >> 4) < rem) {
        f4 v = __builtin_nontemporal_load(q);
        a1 += v;
    }

    f4 s = (a0 + a1) + (a2 + a3);
    // combine the 4 row-groups (lanes i, i^16, i^32, i^48)
    s.x += __shfl_xor(s.x, 16); s.y += __shfl_xor(s.y, 16);
    s.z += __shfl_xor(s.z, 16); s.w += __shfl_xor(s.w, 16);
    s.x += __shfl_xor(s.x, 32); s.y += __shfl_xor(s.y, 32);
    s.z += __shfl_xor(s.z, 32); s.w += __shfl_xor(s.w, 32);

    if ((lane >> 4) == 0) {
        float inv = (cnt > 0) ? 1.f / (float)cnt : 0.f;
        f4 r = s * inv;
        __builtin_nontemporal_store(r, out4 + (size_t)wave * 16 + lane);
    }
}

// Fallback if workspace is too small: per-wave binary search (dword path).
__global__ __launch_bounds__(256) void seg_mean_bs_kernel(const float* __restrict__ feat,
                                                          const int* __restrict__ seg, int N,
                                                          float* __restrict__ out, int S) {
    int wave = (int)((blockIdx.x * blockDim.x + threadIdx.x) >> 6);
    int lane = threadIdx.x & 63;
    if (wave >= S) return;

    int lo = lower_bound_dev(seg, N, wave);
    int hi = lower_bound_dev(seg, N, wave + 1);
    int cnt = hi - lo;

    const float* p = feat + (size_t)lo * 64 + lane;
    float a0 = 0.f, a1 = 0.f, a2 = 0.f, a3 = 0.f;
    int r = lo;
    for (; r + 4 <= hi; r += 4) {
        a0 += p[0];
        a1 += p[64];
        a2 += p[128];
        a3 += p[192];
        p += 256;
    }
    for (; r < hi; ++r) { a0 += *p; p += 64; }
    float acc = (a0 + a1) + (a2 + a3);

    out[(size_t)wave * 64 + lane] = (cnt > 0) ? (acc / (float)cnt) : 0.f;
}

extern "C" void kernel_launch(void* const* d_in, const int* in_sizes, int n_in,
                              void* d_out, int out_size, void* d_ws, size_t ws_size,
                              hipStream_t stream) {
    const float* feat = (const float*)d_in[0];
    const int* seg = (const int*)d_in[1];
    const int N = in_sizes[1];
    const int S = out_size / 64;
    float* out = (float*)d_out;

    const size_t need = (size_t)(S + 1) * sizeof(int);

    if (ws_size >= need) {
        int* starts = (int*)d_ws;
        int total = N + S + 1;
        build_starts_kernel<<<(total + 255) / 256, 256, 0, stream>>>(seg, N, S, starts);
        int main_blocks = (S * 64 + 255) / 256;
        seg_mean_f4_kernel<<<main_blocks, 256, 0, stream>>>(
            (const f4*)feat, starts, (f4*)out, S);
    } else {
        int main_blocks = (S * 64 + 255) / 256;
        seg_mean_bs_kernel<<<main_blocks, 256, 0, stream>>>(feat, seg, N, out, S);
    }
}